// Round 5
// baseline (2592.176 us; speedup 1.0000x reference)
//
#include <hip/hip_runtime.h>

#define T_DIM 256
#define B_DIM 128
#define C_DIM 512
#define H_DIM 512

// LDS (64KB): R0 = x/cell-staging region for waves 0,1 GEMM A (32KB), Pl f32 (32KB)
#define R0H 0
#define PLB 32768

typedef _Float16 half8 __attribute__((ext_vector_type(8)));
typedef float f32x4 __attribute__((ext_vector_type(4)));
typedef unsigned u32x4 __attribute__((ext_vector_type(4)));

__device__ __forceinline__ float sigf(float x) { return 1.0f / (1.0f + __expf(-x)); }
__device__ __forceinline__ float tanhf_(float x) {
  float e = __expf(2.0f * x);
  return (e - 1.0f) / (e + 1.0f);
}

__device__ __forceinline__ half8 cvt8(float4 a, float4 b) {
  half8 h;
  h[0] = (_Float16)a.x; h[1] = (_Float16)a.y; h[2] = (_Float16)a.z; h[3] = (_Float16)a.w;
  h[4] = (_Float16)b.x; h[5] = (_Float16)b.y; h[6] = (_Float16)b.z; h[7] = (_Float16)b.w;
  return h;
}

// ---------------- XCD-local barrier (R3-proven; R4's sc0-load poll FAILED —
// a prior session's ablation already showed scope-flagged load polling is
// wrong/slow here; the inv+plain-load quantum is the working primitive) -------
__device__ __forceinline__ void gbar_arrive(unsigned* slots, int bc, unsigned epoch) {
  __syncthreads();
  if (threadIdx.x == 0) *(volatile unsigned*)(slots + bc) = epoch;
}

__device__ __forceinline__ void gbar_wait_pw(const unsigned* slots, unsigned epoch,
                                             int pollwave) {
  if ((int)(threadIdx.x >> 6) == pollwave) {
    const volatile unsigned* myslot =
        (const volatile unsigned*)(slots + (threadIdx.x & 31));
    int guard = 0;
    for (;;) {
      asm volatile("buffer_inv sc0\n\ts_waitcnt vmcnt(0)" ::: "memory");
      unsigned v = *myslot;
      if (__ballot(v >= epoch) == ~0ull) break;
      if (++guard > (1 << 14)) break;  // fail loud, not dead
    }
  }
  __syncthreads();
  asm volatile("buffer_inv sc0" ::: "memory");      // L1-only inv; data-visibility join
  asm volatile("s_waitcnt vmcnt(0)" ::: "memory");
}

// ---------------- cross-XCD (LLC) primitives (R2/R3-proven) ----------------
__device__ __forceinline__ unsigned sysld_u32(const unsigned* p) {
  unsigned v;
  asm volatile("global_load_dword %0, %1, off sc0 sc1\n\ts_waitcnt vmcnt(0)"
               : "=v"(v) : "v"(p) : "memory");
  return v;
}

// Raw 32-slot LLC poll, NO closing sync (caller owns the join). Call from ONE wave.
__device__ __forceinline__ void xpoll_raw(const unsigned* slots, unsigned epoch) {
  const unsigned* my = slots + (threadIdx.x & 31);
  int guard = 0;
  for (;;) {
    unsigned v = sysld_u32(my);
    if (__ballot(v >= epoch) == ~0ull) break;
    if (++guard > (1 << 15)) break;  // fail loud, not dead
  }
}

__device__ __forceinline__ void xpost(unsigned* flag, unsigned epoch) {
  asm volatile("s_waitcnt vmcnt(0)" ::: "memory");
  asm volatile("global_store_dword %0, %1, off sc0 sc1" ::
                   "v"(flag), "v"(epoch) : "memory");
}

__device__ __forceinline__ void store_llc_h16(_Float16* p, _Float16 v) {
  unsigned u = (unsigned)__builtin_bit_cast(unsigned short, v);
  asm volatile("global_store_short %0, %1, off sc0 sc1" ::
                   "v"(p), "v"(u) : "memory");
}

// Layer-pipelined persistent nested-LSTM — R3 schedule + DIRECT-L2 A-operands.
// Grid 256x256, 1 block/CU. XCD=blockIdx&7; lyr=xcd>>2 (XCDs 0-3 layer 0, 4-7
// layer 1, skewed via 4-deep LLC y0 ring). pgrp=xcd&3 owns rows [32*pgrp,+32);
// bc=blockIdx>>3 owns gate cols [16bc,+16). Wave K-split: wave wv holds B-frags
// K [256wv,+256) -> waves 0,1 = x/cell half, waves 2,3 = h/hi half.
// NEW (R5): the h/hi/cell exchange slabs are stored fragment-linear, so MFMA
// A-fragments are read DIRECTLY from the L2-resident slabs (coalesced 1KB/wave
// global_load_dwordx4) — the serial copy_hhi/copy_r0 phases and their syncs are
// deleted. Same L2 traffic, no LDS round trip, latency hidden under MFMA.
// Visibility: every slab read is ordered after a closing buffer_inv sc0 newer
// than the slab's publishing barrier; WAR on slabs is gated by the same
// barriers as R3. LDS now 64KB: R0 x/cell-staging (waves 0,1 A-source), Pl.
// Windows: end = stage x(t+1)/LLC-copy y0(t+1) + waves01 GEMM1-x + wave3 polls
// (+L0 bak clearance, L1 deferred out-stores); cell = waves23 GEMM2-hi + wave0
// polls.
__global__ __launch_bounds__(256, 1) void nlstm_pipe(
    const float* __restrict__ xin, const float* __restrict__ h0,
    const float* __restrict__ Wg, const float* __restrict__ bgb,
    const float* __restrict__ Wi, const float* __restrict__ bib,
    float* __restrict__ out, unsigned* __restrict__ bar,
    _Float16* __restrict__ y0buf, _Float16* __restrict__ hlcb,
    _Float16* __restrict__ hicb, _Float16* __restrict__ clcb)
{
  __shared__ __align__(16) char smem[65536];
  _Float16* AldsH = (_Float16*)smem;
  float* Pl = (float*)(smem + PLB);

  const int tid  = threadIdx.x;
  const int xcd  = blockIdx.x & 7;
  const int lyr  = xcd >> 2;
  const int pgrp = xcd & 3;
  const int bc   = blockIdx.x >> 3;
  const int wv   = tid >> 6;
  const int lane = tid & 63;
  const int ln   = lane & 15;
  const int kg   = lane >> 4;
  const int pb   = tid >> 4;
  const int pj   = tid & 15;
  const int jglob = bc * 16 + pj;
  const int ncol  = bc * 16 + ln;
  const int r0    = pgrp * 32;

  const int exo = (jglob >> 5) * 1024 + (((jglob >> 3) & 3) * 16 + pb) * 8 + (jglob & 7);

  unsigned* eslots = bar + xcd * 64;       // 32 end slots (local)
  unsigned* cslots = eslots + 32;          // 32 cell slots (local)
  unsigned* fwdS = bar + 512 + pgrp * 32;  // 32 per-block fwd slots (LLC)
  unsigned* bakS = bar + 640 + pgrp * 32;  // 32 per-block back slots (LLC)

  _Float16* hloc0 = hlcb + ((size_t)xcd * 2 + 0) * 16384;
  _Float16* hloc1 = hlcb + ((size_t)xcd * 2 + 1) * 16384;
  _Float16* hilc0 = hicb + ((size_t)xcd * 2 + 0) * 16384;
  _Float16* hilc1 = hicb + ((size_t)xcd * 2 + 1) * 16384;
  _Float16* cbase = clcb + (size_t)xcd * 16384;
  _Float16* y0base = y0buf + (size_t)pgrp * 4 * 16384;  // 4-deep ring

  // ---- weights -> VGPR fp16 frags ----
  half8 wgf[4][8], wif[4][8];
  float bgv[4], biv[4];
#pragma unroll
  for (int g = 0; g < 4; ++g) {
    const float* wgr = Wg + ((size_t)lyr * 2048 + g * 512 + ncol) * 1024 + wv * 256;
    const float* wir = Wi + ((size_t)lyr * 2048 + g * 512 + ncol) * 1024 + wv * 256;
#pragma unroll
    for (int i = 0; i < 8; ++i) {
      const float* p = wgr + i * 32 + kg * 8;
      wgf[g][i] = cvt8(*(const float4*)p, *(const float4*)(p + 4));
      const float* q = wir + i * 32 + kg * 8;
      wif[g][i] = cvt8(*(const float4*)q, *(const float4*)(q + 4));
    }
    bgv[g] = bgb[lyr * 2048 + g * 512 + jglob];
    biv[g] = bib[lyr * 2048 + g * 512 + jglob];
  }

  // ---- initial states (rows pb, pb+16) ----
  float st_c[2], st_ci[2], o_pre[2], outv[2];
  {
    const float* h0l = h0 + (size_t)lyr * 4 * B_DIM * H_DIM + (size_t)(r0 + pb) * H_DIM + jglob;
#pragma unroll
    for (int mt = 0; mt < 2; ++mt) {
      const float* pp = h0l + (size_t)mt * 16 * H_DIM;
      float h_in  = pp[0];
      st_c[mt]    = pp[(size_t)1 * B_DIM * H_DIM];
      float hi_in = pp[(size_t)2 * B_DIM * H_DIM];
      st_ci[mt]   = pp[(size_t)3 * B_DIM * H_DIM];
      hloc0[exo + mt * 512] = (_Float16)h_in;
      hilc0[exo + mt * 512] = (_Float16)hi_in;
      o_pre[mt] = 0.f;
      outv[mt] = 0.f;
    }
  }

  // ---- helpers ----
  auto stage_x = [&](int t) {  // layer 0 only: xin(t) -> R0 (fp16, fragment order)
    const int m = tid & 31;
    const int q = tid >> 5;
    const int mt = m >> 4, mm = m & 15;
    const float* srow = xin + ((size_t)t * B_DIM + r0 + m) * C_DIM;
#pragma unroll
    for (int i = 0; i < 8; ++i) {
      const int chunk = q * 8 + i;
      const int ks = chunk >> 2, kq = chunk & 3;
      const float* p = srow + chunk * 8;
      *(half8*)(AldsH + R0H + ks * 1024 + mt * 512 + (kq * 16 + mm) * 8) =
          cvt8(*(const float4*)p, *(const float4*)(p + 4));
    }
  };
  auto copy_r0_sys = [&](const _Float16* src) {  // 32KB LLC slab -> R0
    u32x4 v[8];
#pragma unroll
    for (int i = 0; i < 8; ++i) {
      const u32x4* p = (const u32x4*)(src + (i * 256 + tid) * 8);
      asm volatile("global_load_dwordx4 %0, %1, off sc0 sc1"
                   : "=v"(v[i]) : "v"(p) : "memory");
    }
    asm volatile("s_waitcnt vmcnt(0)" ::: "memory");
    __builtin_amdgcn_sched_barrier(0);
#pragma unroll
    for (int i = 0; i < 8; ++i)
      *(u32x4*)(AldsH + R0H + (i * 256 + tid) * 8) = v[i];
  };
  // A-fragment MFMA over 8 ks; rb may be LDS (R0) or a GLOBAL slab pointer
  // (fragment-linear layout is identical; global reads are coalesced 1KB/wave).
  auto mfma8 = [&](const _Float16* rb, int ksb, half8 (&wf)[4][8], f32x4 (&acc)[2][4]) {
#pragma unroll
    for (int i = 0; i < 8; ++i) {
      const _Float16* ab = rb + (ksb + i) * 1024 + lane * 8;
      half8 a0 = *(const half8*)(ab);
      half8 a1 = *(const half8*)(ab + 512);
#pragma unroll
      for (int g = 0; g < 4; ++g) {
        acc[0][g] = __builtin_amdgcn_mfma_f32_16x16x32_f16(a0, wf[g][i], acc[0][g], 0, 0, 0);
        acc[1][g] = __builtin_amdgcn_mfma_f32_16x16x32_f16(a1, wf[g][i], acc[1][g], 0, 0, 0);
      }
    }
  };
  auto plw = [&](f32x4 (&acc)[2][4]) {
#pragma unroll
    for (int mt = 0; mt < 2; ++mt)
#pragma unroll
      for (int g = 0; g < 4; ++g)
#pragma unroll
        for (int rr = 0; rr < 4; ++rr)
          Pl[(((g * 2 + mt) * 16 + kg * 4 + rr) * 16 + ln) * 4 + (wv ^ kg)] = acc[mt][g][rr];
  };
  auto plsum = [&](int g, int mt) -> float {
    f32x4 v = *(const f32x4*)(Pl + (((g * 2 + mt) * 16 + pb) * 16 + pj) * 4);
    return v[0] + v[1] + v[2] + v[3];
  };

  unsigned eseq = 0, cseq = 0;

  // ---- init publish + x(0)/y0(0) staging + early GEMM1(0) x-half ----
  gbar_arrive(eslots, bc, ++eseq);
  if (lyr == 0) stage_x(0);
  gbar_wait_pw(eslots, eseq, 3);
  if (lyr == 1) {
    if (wv == 0) xpoll_raw(fwdS, 1u);  // all 32 L0 blocks finished step 0
    __syncthreads();
    copy_r0_sys(y0base + 0);           // y0(0) in ring slot 0
    __syncthreads();
    if (tid == 0) xpost(bakS + bc, 1u);
  }
  if (wv < 2) {
    f32x4 acc[2][4];
#pragma unroll
    for (int mt = 0; mt < 2; ++mt)
#pragma unroll
      for (int g = 0; g < 4; ++g) acc[mt][g] = (f32x4){0.f, 0.f, 0.f, 0.f};
    mfma8(AldsH + R0H, 8 * wv, wgf, acc);
    plw(acc);
  }

  for (int t = 0; t < T_DIM; ++t) {
    const int pr = t & 1;
    _Float16* hrd  = pr ? hloc1 : hloc0;
    _Float16* hwr  = pr ? hloc0 : hloc1;
    _Float16* hird = pr ? hilc1 : hilc0;
    _Float16* hiwr = pr ? hilc0 : hilc1;
    _Float16* y0wr = y0base + (size_t)(t & 3) * 16384;        // L0 writes y0(t)
    _Float16* y0rd = y0base + (size_t)((t + 1) & 3) * 16384;  // L1 end window reads y0(t+1)

    // ---- GEMM1 h-half: waves 2,3 read h(t-1) slab DIRECTLY from L2 ----
    if (wv >= 2) {
      f32x4 acc[2][4];
#pragma unroll
      for (int mt = 0; mt < 2; ++mt)
#pragma unroll
        for (int g = 0; g < 4; ++g) acc[mt][g] = (f32x4){0.f, 0.f, 0.f, 0.f};
      mfma8(hrd, 8 * wv - 16, wgf, acc);
      plw(acc);
    }
    __syncthreads();

    // ---- pointwise 1: cell = sig(f)*c + sig(i)*tanh(gc) ----
#pragma unroll
    for (int mt = 0; mt < 2; ++mt) {
      float gi = plsum(0, mt) + bgv[0];
      float gf = plsum(1, mt) + bgv[1];
      float go = plsum(2, mt) + bgv[2];
      float gc = plsum(3, mt) + bgv[3];
      float cell = sigf(gf) * st_c[mt] + sigf(gi) * tanhf_(gc);
      o_pre[mt] = go;
      cbase[exo + mt * 512] = (_Float16)cell;
    }
    gbar_arrive(cslots, bc, ++cseq);
    // ---- cell window: waves 2,3 GEMM2 hi-half direct from L2; wave0 polls ----
    if (wv >= 2) {
      f32x4 acc[2][4];
#pragma unroll
      for (int mt = 0; mt < 2; ++mt)
#pragma unroll
        for (int g = 0; g < 4; ++g) acc[mt][g] = (f32x4){0.f, 0.f, 0.f, 0.f};
      mfma8(hird, 8 * wv - 16, wif, acc);
      plw(acc);
    }
    gbar_wait_pw(cslots, cseq, 0);  // cell visible XCD-wide (closing inv)

    // ---- GEMM2 cell-half: waves 0,1 read cell slab DIRECTLY from L2 ----
    if (wv < 2) {
      f32x4 acc[2][4];
#pragma unroll
      for (int mt = 0; mt < 2; ++mt)
#pragma unroll
        for (int g = 0; g < 4; ++g) acc[mt][g] = (f32x4){0.f, 0.f, 0.f, 0.f};
      mfma8(cbase, 8 * wv, wif, acc);
      plw(acc);
    }
    __syncthreads();

    // ---- pointwise 2: inner cell; outputs; c := hi_n ----
#pragma unroll
    for (int mt = 0; mt < 2; ++mt) {
      float i2 = plsum(0, mt) + biv[0];
      float f2 = plsum(1, mt) + biv[1];
      float o2 = plsum(2, mt) + biv[2];
      float c2 = plsum(3, mt) + biv[3];
      float ci_n = sigf(f2) * st_ci[mt] + sigf(i2) * tanhf_(c2);
      float hi_n = sigf(o2) * tanhf_(ci_n);
      float h_n  = sigf(o_pre[mt]) * tanhf_(hi_n);
      st_ci[mt] = ci_n;
      st_c[mt]  = hi_n;  // reference carry: c <- hi_n
      hiwr[exo + mt * 512] = (_Float16)hi_n;
      hwr[exo + mt * 512]  = (_Float16)h_n;
      if (lyr == 0) {
        store_llc_h16(y0wr + exo + mt * 512, (_Float16)h_n);
      } else {
        outv[mt] = h_n;  // deferred: stored post-arrive (out never read in-kernel)
      }
    }

    gbar_arrive(eslots, bc, ++eseq);  // end barrier: arrive (drains y0/h/hi stores)
    // ---- end window ----
    if (lyr == 0) {
      if (tid == 0) xpost(fwdS + bc, (unsigned)(t + 1));  // unblock L1 first
      if (t + 1 < T_DIM) {
        stage_x(t + 1);
        __syncthreads();
        if (wv < 2) {  // early GEMM1(t+1) x-half from LDS R0
          f32x4 acc[2][4];
#pragma unroll
          for (int mt = 0; mt < 2; ++mt)
#pragma unroll
            for (int g = 0; g < 4; ++g) acc[mt][g] = (f32x4){0.f, 0.f, 0.f, 0.f};
          mfma8(AldsH + R0H, 8 * wv, wgf, acc);
          plw(acc);
        } else if (wv == 3 && t >= 2) {
          // ring clearance for step t+1's slab ((t+1)&3, holds y0(t-3)):
          // consumed when bak >= t-2. Overlaps the end poll.
          xpoll_raw(bakS, (unsigned)(t - 2));
        }
      }
    } else {
      // deferred out stores: HBM write-ACK drains at the join, off critical path
#pragma unroll
      for (int mt = 0; mt < 2; ++mt)
        out[((size_t)t * B_DIM + (r0 + pb + mt * 16)) * H_DIM + jglob] = outv[mt];
      if (t + 1 < T_DIM) {
        if (wv == 0) xpoll_raw(fwdS, (unsigned)(t + 2));  // L0 past step t+1
        __syncthreads();
        copy_r0_sys(y0rd);  // x(t+1) = y0(t+1) -> R0
        __syncthreads();
        if (tid == 0) xpost(bakS + bc, (unsigned)(t + 2));  // consumed y0(t+1)
        if (wv < 2) {  // early GEMM1(t+1) x-half from LDS R0
          f32x4 acc[2][4];
#pragma unroll
          for (int mt = 0; mt < 2; ++mt)
#pragma unroll
            for (int g = 0; g < 4; ++g) acc[mt][g] = (f32x4){0.f, 0.f, 0.f, 0.f};
          mfma8(AldsH + R0H, 8 * wv, wgf, acc);
          plw(acc);
        }
      }
    }
    gbar_wait_pw(eslots, eseq, 3);  // wave3 polls; h/hi visible for next step
  }
}

extern "C" void kernel_launch(void* const* d_in, const int* in_sizes, int n_in,
                              void* d_out, int out_size, void* d_ws, size_t ws_size,
                              hipStream_t stream) {
  const float* xin = (const float*)d_in[0];
  const float* h0  = (const float*)d_in[1];
  const float* Wg  = (const float*)d_in[2];
  const float* bg  = (const float*)d_in[3];
  const float* Wi  = (const float*)d_in[4];
  const float* bi  = (const float*)d_in[5];
  float* out = (float*)d_out;

  // ws layout:
  //   [0,4KB)  flags: 8 XCD x 64 local (2KB) | fwd 4x32 @ +512 | back 4x32 @ +640
  //   y0buf  [4 pair][4 ring][16384] fp16 = 512KB  (LLC cross-layer feed)
  //   hlcb   [8 xcd][2 parity][16384] fp16 = 512KB
  //   hicb   [8 xcd][2 parity][16384] fp16 = 512KB
  //   clcb   [8 xcd][16384] fp16 = 256KB
  unsigned* bar  = (unsigned*)d_ws;
  _Float16* y0b  = (_Float16*)((char*)d_ws + 4096);
  _Float16* hlcb = y0b + (size_t)4 * 4 * 16384;
  _Float16* hicb = hlcb + (size_t)8 * 2 * 16384;
  _Float16* clcb = hicb + (size_t)8 * 2 * 16384;

  hipMemsetAsync(d_ws, 0, 4096, stream);  // all flag epochs start at 0

  nlstm_pipe<<<dim3(256), dim3(256), 0, stream>>>(
      xin, h0, Wg, bg, Wi, bi, out, bar, y0b, hlcb, hicb, clcb);
}